// Round 3
// baseline (408.838 us; speedup 1.0000x reference)
//
#include <hip/hip_runtime.h>

typedef unsigned short u16;
typedef unsigned int u32;
typedef _Float16 f16;
typedef __attribute__((ext_vector_type(8))) f16 v8h;
typedef __attribute__((ext_vector_type(4))) f16 v4h;
typedef __attribute__((ext_vector_type(16))) float v16f;

#define BN 16
#define CHN 64
#define HH 192
#define WW 192
#define HWSZ 36864
#define KDY 4
#define HIDN 17
#define NG 8
#define TEMP_ 30.0f
#define EPSV 1e-5f
#define NSLOPE 0.01f
#define NTILE 144        // HWSZ / 256

// conv tiling: 4 rows x 32 cols output tile per workgroup, halo 6x34
#define TR 4
#define TC 32
#define HR 6
#define HC 34
#define PSTR 34          // u32 stride per halo pixel: 32 ci-pairs + 2 pad
#define ROWH (HC * PSTR * 2)   // halo row stride in halves
#define NCHUNK (HR * HC * 8)   // 1632 16B chunks per halo tile
#define NBLK 4608              // 48 row-tiles * 6 col-tiles * 16 b

__device__ float g_pp[BN * NTILE * CHN];                   // per-tile pool partials
__device__ float g_attn[BN * KDY];
__device__ float g_stats[BN * NG * 2];
__device__ __align__(16) f16 g_filt[BN * 9 * CHN * CHN];   // [b][tap][co][ci], 1.18 MB
__device__ __align__(16) f16 g_xh[(size_t)BN * HWSZ * CHN]; // x in fp16 NHWC, 75.5 MB
__device__ __align__(16) f16 g_yh[(size_t)BN * CHN * HWSZ]; // conv out fp16 NCHW, 75.5 MB

// ---- Stage 1: NCHW fp32 -> NHWC fp16 transpose, fused global-avg-pool partials
__global__ void __launch_bounds__(256) trans_pool_kernel(const float* __restrict__ x) {
    __shared__ u32 ts[256 * 34];                           // 34816 B
    const int b = blockIdx.y, tile = blockIdx.x;
    const int t = threadIdx.x;
    const int p0 = tile * 256;
    const float* xb = x + (size_t)b * CHN * HWSZ + p0;
    #pragma unroll 4
    for (int cp = 0; cp < 32; cp++) {                      // coalesced per-channel reads
        float v0 = xb[(size_t)(2 * cp) * HWSZ + t];
        float v1 = xb[(size_t)(2 * cp + 1) * HWSZ + t];
        u32 pk = (u32)__builtin_bit_cast(u16, (f16)v0)
               | ((u32)__builtin_bit_cast(u16, (f16)v1) << 16);
        ts[t * 34 + cp] = pk;
    }
    __syncthreads();
    // write pixel t (128 B contiguous) to g_xh
    f16* dp = g_xh + ((size_t)b * HWSZ + p0 + t) * CHN;
    const u32* src = ts + t * 34;
    #pragma unroll
    for (int i = 0; i < 8; i++) {                          // 136B base: 8B-aligned LDS reads
        uint2 a = *(const uint2*)(src + 4 * i);
        uint2 c = *(const uint2*)(src + 4 * i + 2);
        ((uint4*)dp)[i] = make_uint4(a.x, a.y, c.x, c.y);
    }
    // pool partials: thread t sums ci-pair (t&31) over 32-pixel segment (t>>5)
    const int cp = t & 31, seg = t >> 5;
    float s0 = 0.f, s1 = 0.f;
    for (int p = 0; p < 32; p++) {
        u32 pk = ts[(seg * 32 + p) * 34 + cp];
        s0 += (float)__builtin_bit_cast(f16, (u16)(pk & 0xffffu));
        s1 += (float)__builtin_bit_cast(f16, (u16)(pk >> 16));
    }
    s0 += __shfl_down(s0, 32);                             // combine seg pair within wave
    s1 += __shfl_down(s1, 32);
    __syncthreads();
    float* ps = (float*)ts;                                // reuse LDS for cross-wave combine
    const int lane = t & 63, w = t >> 6;
    if (lane < 32) { ps[(w * 32 + lane) * 2] = s0; ps[(w * 32 + lane) * 2 + 1] = s1; }
    __syncthreads();
    if (t < 32) {
        float a0 = ps[t * 2] + ps[(32 + t) * 2] + ps[(64 + t) * 2] + ps[(96 + t) * 2];
        float a1 = ps[t * 2 + 1] + ps[(32 + t) * 2 + 1]
                 + ps[(64 + t) * 2 + 1] + ps[(96 + t) * 2 + 1];
        float* gp = g_pp + ((size_t)b * NTILE + tile) * CHN;
        gp[2 * t] = a0; gp[2 * t + 1] = a1;
    }
}

// ---- Stage 2: pool-partial reduce + attention MLP + softmax; zeroes GN stats
__global__ void __launch_bounds__(256) attn_kernel(const float* __restrict__ w1,
                                                   const float* __restrict__ w2,
                                                   const float* __restrict__ b2) {
    __shared__ float red[256];
    __shared__ float pr[CHN];
    __shared__ float hs[HIDN];
    const int b = blockIdx.x, t = threadIdx.x;
    if (t < NG * 2) g_stats[b * NG * 2 + t] = 0.f;
    const int c = t & 63, part = t >> 6;                   // 4 parts x 36 tiles
    const float* gp = g_pp + (size_t)b * NTILE * CHN + c;
    float s = 0.f;
    #pragma unroll 4
    for (int i = part * 36; i < part * 36 + 36; i++) s += gp[i * CHN];
    red[t] = s;
    __syncthreads();
    if (t < CHN)
        pr[t] = (red[t] + red[t + 64] + red[t + 128] + red[t + 192]) * (1.0f / HWSZ);
    __syncthreads();
    if (t < HIDN) {
        float a = 0.f;
        for (int cc = 0; cc < CHN; cc++) a += w1[t * CHN + cc] * pr[cc];
        hs[t] = fmaxf(a, 0.f);
    }
    __syncthreads();
    if (t == 0) {
        float scv[KDY]; float m = -3e38f;
        #pragma unroll
        for (int k = 0; k < KDY; k++) {
            float sc = b2[k];
            for (int h = 0; h < HIDN; h++) sc += w2[k * HIDN + h] * hs[h];
            sc *= (1.0f / TEMP_);
            scv[k] = sc; m = fmaxf(m, sc);
        }
        float den = 0.f;
        #pragma unroll
        for (int k = 0; k < KDY; k++) { scv[k] = __expf(scv[k] - m); den += scv[k]; }
        float rd = 1.f / den;
        #pragma unroll
        for (int k = 0; k < KDY; k++) g_attn[b * KDY + k] = scv[k] * rd;
    }
}

// ---- Stage 3: synthesize fp16 filters [b][tap][co][ci]
__global__ void filt_kernel(const float* __restrict__ wts) {
    __shared__ float at[BN * KDY];
    if (threadIdx.x < BN * KDY) at[threadIdx.x] = g_attn[threadIdx.x];
    __syncthreads();
    int t = blockIdx.x * 256 + threadIdx.x;     // < 36864
    int tap = t / 4096;
    int co = (t >> 6) & 63;
    int ci = t & 63;
    float w0 = wts[((0 * CHN + co) * CHN + ci) * 9 + tap];
    float w1 = wts[((1 * CHN + co) * CHN + ci) * 9 + tap];
    float w2 = wts[((2 * CHN + co) * CHN + ci) * 9 + tap];
    float w3 = wts[((3 * CHN + co) * CHN + ci) * 9 + tap];
    #pragma unroll
    for (int b = 0; b < BN; b++) {
        float v = at[b * 4] * w0 + at[b * 4 + 1] * w1
                + at[b * 4 + 2] * w2 + at[b * 4 + 3] * w3;
        g_filt[((b * 9 + tap) * CHN + co) * CHN + ci] = (f16)v;
    }
}

// ---- Stage 4: MFMA implicit-GEMM conv + fused GN stats
// 4608 blocks (XCD-chunked), 256 thr / 4 waves. Wave (wr,wc): rows {2wr,2wr+1},
// co band wc*32..+31. 27.7KB LDS -> 5 blocks/CU = 5 waves/SIMD.
// A-frag: 4 v8h cur + 4 prefetch (next tap). Output fp16 NCHW + GN stats.
__global__ void __launch_bounds__(256, 5) conv_kernel() {
    __shared__ __align__(16) u32 xs[HR * HC * PSTR];   // 27744 B
    __shared__ float gsum[NG], gsq[NG];
    const int bid = blockIdx.x;
    const int swz = (bid & 7) * 576 + (bid >> 3);      // 4608 = 8 * 576, bijective
    const int b = swz / 288;
    const int rem = swz - b * 288;                     // 48 row-tiles * 6 col-tiles
    const int r0 = (rem / 6) * TR, c0 = (rem % 6) * TC;
    const int tid = threadIdx.x;
    const int w = tid >> 6, lane = tid & 63;
    const int wr = w >> 1, wc = w & 1;
    const int n = lane & 31, hi = lane >> 5;
    if (tid < NG) { gsum[tid] = 0.f; gsq[tid] = 0.f; }

    // staging phase 1: issue all loads (clamped addresses, all in flight)
    const f16* xhb = g_xh + (size_t)b * HWSZ * CHN;
    uint4 rv[7];
    #pragma unroll
    for (int i = 0; i < 7; i++) {
        int l = tid + i * 256;
        int pix = l >> 3, part = l & 7;
        int hr = pix / HC, hc = pix - hr * HC;
        int gr = r0 - 1 + hr, gc = c0 - 1 + hc;
        bool ok = (l < NCHUNK) && ((unsigned)gr < HH) && ((unsigned)gc < WW);
        size_t off = ok ? ((size_t)(gr * WW + gc) * CHN + part * 8) : 0;
        rv[i] = *(const uint4*)(xhb + off);
    }
    // staging phase 2: LDS writes (zero OOB)
    #pragma unroll
    for (int i = 0; i < 7; i++) {
        int l = tid + i * 256;
        if (l < NCHUNK) {
            int pix = l >> 3, part = l & 7;
            int hr = pix / HC, hc = pix - hr * HC;
            int gr = r0 - 1 + hr, gc = c0 - 1 + hc;
            bool ok = ((unsigned)gr < HH) && ((unsigned)gc < WW);
            uint4 v = ok ? rv[i] : make_uint4(0, 0, 0, 0);
            u32* d = xs + pix * PSTR + part * 4;       // byte = pix*136+part*16: 8B aligned
            *(uint2*)d = make_uint2(v.x, v.y);
            *(uint2*)(d + 2) = make_uint2(v.z, v.w);
        }
    }
    __syncthreads();

    const f16* xsh = (const f16*)xs;
    const f16* fb = g_filt + (size_t)b * 9 * CHN * CHN
                  + (size_t)(wc * 32 + n) * CHN + hi * 8;
    v16f acc0 = {}, acc1 = {};

    v8h A[4];
    #pragma unroll
    for (int kb = 0; kb < 4; kb++) A[kb] = *(const v8h*)(fb + kb * 16);
    #pragma unroll
    for (int tap = 0; tap < 9; tap++) {
        v8h P[4];
        if (tap < 8) {                                     // prefetch next tap's A (L2-hot)
            const f16* fp = fb + (tap + 1) * (CHN * CHN);
            #pragma unroll
            for (int kb = 0; kb < 4; kb++) P[kb] = *(const v8h*)(fp + kb * 16);
        }
        const int dy = tap / 3, dx = tap - 3 * (tap / 3);
        const f16* xr = xsh + ((2 * wr + dy) * HC + (n + dx)) * (PSTR * 2) + hi * 8;
        __builtin_amdgcn_s_setprio(1);
        #pragma unroll
        for (int kb = 0; kb < 4; kb++) {
            v4h lo0 = *(const v4h*)(xr + kb * 16);
            v4h up0 = *(const v4h*)(xr + kb * 16 + 4);
            v4h lo1 = *(const v4h*)(xr + kb * 16 + ROWH);
            v4h up1 = *(const v4h*)(xr + kb * 16 + 4 + ROWH);
            v8h b0 = __builtin_shufflevector(lo0, up0, 0, 1, 2, 3, 4, 5, 6, 7);
            v8h b1 = __builtin_shufflevector(lo1, up1, 0, 1, 2, 3, 4, 5, 6, 7);
            acc0 = __builtin_amdgcn_mfma_f32_32x32x16_f16(A[kb], b0, acc0, 0, 0, 0);
            acc1 = __builtin_amdgcn_mfma_f32_32x32x16_f16(A[kb], b1, acc1, 0, 0, 0);
        }
        __builtin_amdgcn_s_setprio(0);
        if (tap < 8) {
            #pragma unroll
            for (int kb = 0; kb < 4; kb++) A[kb] = P[kb];
        }
    }

    // epilogue: fp16 scatter to g_yh + fused GN partial stats (fp32 from accs)
    float sg[4] = {0.f, 0.f, 0.f, 0.f}, sq[4] = {0.f, 0.f, 0.f, 0.f};
    f16* yb = g_yh + (size_t)b * CHN * HWSZ + (size_t)(r0 + 2 * wr) * WW + (c0 + n);
    #pragma unroll
    for (int r = 0; r < 16; r++) {
        int co = wc * 32 + (r & 3) + 8 * (r >> 2) + 4 * hi;
        float a0 = acc0[r], a1 = acc1[r];
        yb[(size_t)co * HWSZ] = (f16)a0;
        yb[(size_t)co * HWSZ + WW] = (f16)a1;
        int gl = r >> 2;
        sg[gl] += a0 + a1; sq[gl] += a0 * a0 + a1 * a1;
    }
    #pragma unroll
    for (int gl = 0; gl < 4; gl++) {
        float s = sg[gl], q = sq[gl];
        #pragma unroll
        for (int off = 32; off > 0; off >>= 1) {
            s += __shfl_down(s, off);
            q += __shfl_down(q, off);
        }
        if (lane == 0) { atomicAdd(&gsum[4 * wc + gl], s); atomicAdd(&gsq[4 * wc + gl], q); }
    }
    __syncthreads();
    if (tid < 2 * NG) {
        int g = tid >> 1, which = tid & 1;
        atomicAdd(&g_stats[(b * NG + g) * 2 + which], which ? gsq[g] : gsum[g]);
    }
}

// ---- Stage 5: GroupNorm apply + LeakyReLU: read fp16 g_yh, write fp32 out
// 2304 blocks grid-stride x8; chunk of 2048 elems lies within one (b,co):
// stats/scale math is block-uniform (scalar), threads do pure vector IO.
__global__ void __launch_bounds__(256) norm_kernel(float* __restrict__ out,
                                                   const float* __restrict__ gamma,
                                                   const float* __restrict__ beta) {
    const int tid = threadIdx.x;
    const float invN = 1.0f / (8.0f * HWSZ);
    #pragma unroll
    for (int it = 0; it < 8; it++) {
        int ch = it * 2304 + blockIdx.x;           // chunk of 2048 elems, 18 per (b,co)
        int bco = ch / 18;                          // = b*64 + co
        int b = bco >> 6, co = bco & 63;
        int g = co >> 3;
        float mean = g_stats[(b * NG + g) * 2 + 0] * invN;
        float var = fmaxf(g_stats[(b * NG + g) * 2 + 1] * invN - mean * mean, 0.f);
        float sc = rsqrtf(var + EPSV) * gamma[co];
        float sh = beta[co] - mean * sc;
        size_t base = (size_t)ch * 2048 + tid * 8;
        v8h v = *(const v8h*)(g_yh + base);
        float vv[8];
        #pragma unroll
        for (int t = 0; t < 8; t++) {
            float a = (float)v[t] * sc + sh;
            vv[t] = a >= 0.f ? a : NSLOPE * a;
        }
        float4* op = (float4*)(out + base);
        op[0] = make_float4(vv[0], vv[1], vv[2], vv[3]);
        op[1] = make_float4(vv[4], vv[5], vv[6], vv[7]);
    }
}

extern "C" void kernel_launch(void* const* d_in, const int* in_sizes, int n_in,
                              void* d_out, int out_size, void* d_ws, size_t ws_size,
                              hipStream_t stream) {
    const float* x     = (const float*)d_in[0];
    const float* w1    = (const float*)d_in[1];
    const float* w2    = (const float*)d_in[2];
    const float* b2    = (const float*)d_in[3];
    const float* wts   = (const float*)d_in[4];
    const float* gamma = (const float*)d_in[5];
    const float* beta  = (const float*)d_in[6];
    float* out = (float*)d_out;

    dim3 tg(NTILE, BN);
    trans_pool_kernel<<<tg, 256, 0, stream>>>(x);
    attn_kernel<<<BN, 256, 0, stream>>>(w1, w2, b2);
    filt_kernel<<<144, 256, 0, stream>>>(wts);
    conv_kernel<<<NBLK, 256, 0, stream>>>();
    norm_kernel<<<2304, 256, 0, stream>>>(out, gamma, beta);
}

// Round 4
// 377.646 us; speedup vs baseline: 1.0826x; 1.0826x over previous
//
#include <hip/hip_runtime.h>

typedef unsigned short u16;
typedef unsigned int u32;
typedef _Float16 f16;
typedef __attribute__((ext_vector_type(8))) f16 v8h;
typedef __attribute__((ext_vector_type(4))) f16 v4h;
typedef __attribute__((ext_vector_type(16))) float v16f;

#define BN 16
#define CHN 64
#define HH 192
#define WW 192
#define HWSZ 36864
#define KDY 4
#define HIDN 17
#define NG 8
#define TEMP_ 30.0f
#define EPSV 1e-5f
#define NSLOPE 0.01f
#define NTILE 144        // HWSZ / 256

// conv tiling: 4 rows x 32 cols output tile per workgroup, halo 6x34
#define TR 4
#define TC 32
#define HR 6
#define HC 34
#define PSTR 34          // u32 stride per halo pixel: 32 ci-pairs + 2 pad
#define ROWH (HC * PSTR * 2)   // halo row stride in halves
#define NCHUNK (HR * HC * 8)   // 1632 16B chunks per halo tile
#define NBLK 4608              // 48 row-tiles * 6 col-tiles * 16 b
#define TAPH 4096              // halves per tap in frag-major g_filt: 2 wc * 4 kb * 32 n * 16

__device__ float g_pp[BN * NTILE * CHN];                   // per-tile pool partials
__device__ float g_attn[BN * KDY];
__device__ float g_stats[BN * NG * 2];
// frag-major filters: [b][tap][wc][kb][n][hi][8] -> one wave A-load = 1KB contiguous
__device__ __align__(16) f16 g_filt[BN * 9 * TAPH];        // 1.18 MB
__device__ __align__(16) f16 g_xh[(size_t)BN * HWSZ * CHN]; // x in fp16 NHWC, 75.5 MB
__device__ __align__(16) f16 g_yh[(size_t)BN * CHN * HWSZ]; // conv out fp16 NCHW, 75.5 MB

// ---- Stage 1: NCHW fp32 -> NHWC fp16 transpose, fused global-avg-pool partials
__global__ void __launch_bounds__(256) trans_pool_kernel(const float* __restrict__ x) {
    __shared__ u32 ts[256 * 34];                           // 34816 B
    const int b = blockIdx.y, tile = blockIdx.x;
    const int t = threadIdx.x;
    const int p0 = tile * 256;
    const float* xb = x + (size_t)b * CHN * HWSZ + p0;
    #pragma unroll 4
    for (int cp = 0; cp < 32; cp++) {                      // coalesced per-channel reads
        float v0 = xb[(size_t)(2 * cp) * HWSZ + t];
        float v1 = xb[(size_t)(2 * cp + 1) * HWSZ + t];
        u32 pk = (u32)__builtin_bit_cast(u16, (f16)v0)
               | ((u32)__builtin_bit_cast(u16, (f16)v1) << 16);
        ts[t * 34 + cp] = pk;
    }
    __syncthreads();
    // write pixel t (128 B contiguous) to g_xh
    f16* dp = g_xh + ((size_t)b * HWSZ + p0 + t) * CHN;
    const u32* src = ts + t * 34;
    #pragma unroll
    for (int i = 0; i < 8; i++) {                          // 136B base: 8B-aligned LDS reads
        uint2 a = *(const uint2*)(src + 4 * i);
        uint2 c = *(const uint2*)(src + 4 * i + 2);
        ((uint4*)dp)[i] = make_uint4(a.x, a.y, c.x, c.y);
    }
    // pool partials: thread t sums ci-pair (t&31) over 32-pixel segment (t>>5)
    const int cp = t & 31, seg = t >> 5;
    float s0 = 0.f, s1 = 0.f;
    for (int p = 0; p < 32; p++) {
        u32 pk = ts[(seg * 32 + p) * 34 + cp];
        s0 += (float)__builtin_bit_cast(f16, (u16)(pk & 0xffffu));
        s1 += (float)__builtin_bit_cast(f16, (u16)(pk >> 16));
    }
    s0 += __shfl_down(s0, 32);                             // combine seg pair within wave
    s1 += __shfl_down(s1, 32);
    __syncthreads();
    float* ps = (float*)ts;                                // reuse LDS for cross-wave combine
    const int lane = t & 63, w = t >> 6;
    if (lane < 32) { ps[(w * 32 + lane) * 2] = s0; ps[(w * 32 + lane) * 2 + 1] = s1; }
    __syncthreads();
    if (t < 32) {
        float a0 = ps[t * 2] + ps[(32 + t) * 2] + ps[(64 + t) * 2] + ps[(96 + t) * 2];
        float a1 = ps[t * 2 + 1] + ps[(32 + t) * 2 + 1]
                 + ps[(64 + t) * 2 + 1] + ps[(96 + t) * 2 + 1];
        float* gp = g_pp + ((size_t)b * NTILE + tile) * CHN;
        gp[2 * t] = a0; gp[2 * t + 1] = a1;
    }
}

// ---- Stage 2: pool-partial reduce + attention MLP + softmax; zeroes GN stats
__global__ void __launch_bounds__(256) attn_kernel(const float* __restrict__ w1,
                                                   const float* __restrict__ w2,
                                                   const float* __restrict__ b2) {
    __shared__ float red[256];
    __shared__ float pr[CHN];
    __shared__ float hs[HIDN];
    const int b = blockIdx.x, t = threadIdx.x;
    if (t < NG * 2) g_stats[b * NG * 2 + t] = 0.f;
    const int c = t & 63, part = t >> 6;                   // 4 parts x 36 tiles
    const float* gp = g_pp + (size_t)b * NTILE * CHN + c;
    float s = 0.f;
    #pragma unroll 4
    for (int i = part * 36; i < part * 36 + 36; i++) s += gp[i * CHN];
    red[t] = s;
    __syncthreads();
    if (t < CHN)
        pr[t] = (red[t] + red[t + 64] + red[t + 128] + red[t + 192]) * (1.0f / HWSZ);
    __syncthreads();
    if (t < HIDN) {
        float a = 0.f;
        for (int cc = 0; cc < CHN; cc++) a += w1[t * CHN + cc] * pr[cc];
        hs[t] = fmaxf(a, 0.f);
    }
    __syncthreads();
    if (t == 0) {
        float scv[KDY]; float m = -3e38f;
        #pragma unroll
        for (int k = 0; k < KDY; k++) {
            float sc = b2[k];
            for (int h = 0; h < HIDN; h++) sc += w2[k * HIDN + h] * hs[h];
            sc *= (1.0f / TEMP_);
            scv[k] = sc; m = fmaxf(m, sc);
        }
        float den = 0.f;
        #pragma unroll
        for (int k = 0; k < KDY; k++) { scv[k] = __expf(scv[k] - m); den += scv[k]; }
        float rd = 1.f / den;
        #pragma unroll
        for (int k = 0; k < KDY; k++) g_attn[b * KDY + k] = scv[k] * rd;
    }
}

// ---- Stage 3: synthesize fp16 filters, frag-major [b][tap][wc][kb][n][hi][8]
__global__ void filt_kernel(const float* __restrict__ wts) {
    __shared__ float at[BN * KDY];
    if (threadIdx.x < BN * KDY) at[threadIdx.x] = g_attn[threadIdx.x];
    __syncthreads();
    int t = blockIdx.x * 256 + threadIdx.x;     // < 36864
    int tap = t / 4096;
    int co = (t >> 6) & 63;
    int ci = t & 63;
    float w0 = wts[((0 * CHN + co) * CHN + ci) * 9 + tap];
    float w1 = wts[((1 * CHN + co) * CHN + ci) * 9 + tap];
    float w2 = wts[((2 * CHN + co) * CHN + ci) * 9 + tap];
    float w3 = wts[((3 * CHN + co) * CHN + ci) * 9 + tap];
    const int wc = co >> 5, n = co & 31;
    const int kb = ci >> 4, rest = ci & 15;                // rest = hi*8 + e
    const size_t dst = (size_t)tap * TAPH + wc * 2048 + kb * 512 + n * 16 + rest;
    #pragma unroll
    for (int b = 0; b < BN; b++) {
        float v = at[b * 4] * w0 + at[b * 4 + 1] * w1
                + at[b * 4 + 2] * w2 + at[b * 4 + 3] * w3;
        g_filt[(size_t)b * 9 * TAPH + dst] = (f16)v;
    }
}

// ---- Stage 4: MFMA implicit-GEMM conv + fused GN stats
// 4608 blocks (XCD-chunked), 4 waves. Wave (wr,wc): rows {2wr,2wr+1}, co band wc*32.
// A-loads now 1KB contiguous per wave instr (frag-major g_filt), distance-2 prefetch.
__global__ void __launch_bounds__(256, 5) conv_kernel() {
    __shared__ __align__(16) u32 xs[HR * HC * PSTR];   // 27744 B
    __shared__ float gsum[NG], gsq[NG];
    const int bid = blockIdx.x;
    const int swz = (bid & 7) * 576 + (bid >> 3);      // 4608 = 8 * 576, bijective
    const int b = swz / 288;
    const int rem = swz - b * 288;                     // 48 row-tiles * 6 col-tiles
    const int r0 = (rem / 6) * TR, c0 = (rem % 6) * TC;
    const int tid = threadIdx.x;
    const int w = tid >> 6, lane = tid & 63;
    const int wr = w >> 1, wc = w & 1;
    const int n = lane & 31, hi = lane >> 5;
    if (tid < NG) { gsum[tid] = 0.f; gsq[tid] = 0.f; }

    // staging phase 1: issue all loads (clamped addresses, all in flight)
    const f16* xhb = g_xh + (size_t)b * HWSZ * CHN;
    uint4 rv[7];
    #pragma unroll
    for (int i = 0; i < 7; i++) {
        int l = tid + i * 256;
        int pix = l >> 3, part = l & 7;
        int hr = pix / HC, hc = pix - hr * HC;
        int gr = r0 - 1 + hr, gc = c0 - 1 + hc;
        bool ok = (l < NCHUNK) && ((unsigned)gr < HH) && ((unsigned)gc < WW);
        size_t off = ok ? ((size_t)(gr * WW + gc) * CHN + part * 8) : 0;
        rv[i] = *(const uint4*)(xhb + off);
    }
    // staging phase 2: LDS writes (zero OOB)
    #pragma unroll
    for (int i = 0; i < 7; i++) {
        int l = tid + i * 256;
        if (l < NCHUNK) {
            int pix = l >> 3, part = l & 7;
            int hr = pix / HC, hc = pix - hr * HC;
            int gr = r0 - 1 + hr, gc = c0 - 1 + hc;
            bool ok = ((unsigned)gr < HH) && ((unsigned)gc < WW);
            uint4 v = ok ? rv[i] : make_uint4(0, 0, 0, 0);
            u32* d = xs + pix * PSTR + part * 4;       // byte = pix*136+part*16: 8B aligned
            *(uint2*)d = make_uint2(v.x, v.y);
            *(uint2*)(d + 2) = make_uint2(v.z, v.w);
        }
    }
    __syncthreads();

    const f16* xsh = (const f16*)xs;
    // frag-major base: lane offset n*16 + hi*8 within a [kb] chunk of 512 halves
    const f16* fb = g_filt + (size_t)b * 9 * TAPH + wc * 2048 + n * 16 + hi * 8;
    v16f acc0 = {}, acc1 = {};

    v8h A[9][4];                                       // static-indexed, dist-2 prefetch
    #pragma unroll
    for (int kb = 0; kb < 4; kb++) {
        A[0][kb] = *(const v8h*)(fb + kb * 512);
        A[1][kb] = *(const v8h*)(fb + TAPH + kb * 512);
    }
    #pragma unroll
    for (int tap = 0; tap < 9; tap++) {
        if (tap < 7) {                                 // prefetch tap+2 (contiguous 1KB/instr)
            const f16* fp = fb + (size_t)(tap + 2) * TAPH;
            #pragma unroll
            for (int kb = 0; kb < 4; kb++) A[tap + 2][kb] = *(const v8h*)(fp + kb * 512);
        }
        const int dy = tap / 3, dx = tap - 3 * (tap / 3);
        const f16* xr = xsh + ((2 * wr + dy) * HC + (n + dx)) * (PSTR * 2) + hi * 8;
        __builtin_amdgcn_s_setprio(1);
        #pragma unroll
        for (int kb = 0; kb < 4; kb++) {
            v4h lo0 = *(const v4h*)(xr + kb * 16);
            v4h up0 = *(const v4h*)(xr + kb * 16 + 4);
            v4h lo1 = *(const v4h*)(xr + kb * 16 + ROWH);
            v4h up1 = *(const v4h*)(xr + kb * 16 + 4 + ROWH);
            v8h b0 = __builtin_shufflevector(lo0, up0, 0, 1, 2, 3, 4, 5, 6, 7);
            v8h b1 = __builtin_shufflevector(lo1, up1, 0, 1, 2, 3, 4, 5, 6, 7);
            acc0 = __builtin_amdgcn_mfma_f32_32x32x16_f16(A[tap][kb], b0, acc0, 0, 0, 0);
            acc1 = __builtin_amdgcn_mfma_f32_32x32x16_f16(A[tap][kb], b1, acc1, 0, 0, 0);
        }
        __builtin_amdgcn_s_setprio(0);
    }

    // epilogue: fp16 scatter to g_yh + fused GN partial stats (fp32 from accs)
    float sg[4] = {0.f, 0.f, 0.f, 0.f}, sq[4] = {0.f, 0.f, 0.f, 0.f};
    f16* yb = g_yh + (size_t)b * CHN * HWSZ + (size_t)(r0 + 2 * wr) * WW + (c0 + n);
    #pragma unroll
    for (int r = 0; r < 16; r++) {
        int co = wc * 32 + (r & 3) + 8 * (r >> 2) + 4 * hi;
        float a0 = acc0[r], a1 = acc1[r];
        yb[(size_t)co * HWSZ] = (f16)a0;
        yb[(size_t)co * HWSZ + WW] = (f16)a1;
        int gl = r >> 2;
        sg[gl] += a0 + a1; sq[gl] += a0 * a0 + a1 * a1;
    }
    #pragma unroll
    for (int gl = 0; gl < 4; gl++) {
        float s = sg[gl], q = sq[gl];
        #pragma unroll
        for (int off = 32; off > 0; off >>= 1) {
            s += __shfl_down(s, off);
            q += __shfl_down(q, off);
        }
        if (lane == 0) { atomicAdd(&gsum[4 * wc + gl], s); atomicAdd(&gsq[4 * wc + gl], q); }
    }
    __syncthreads();
    if (tid < 2 * NG) {
        int g = tid >> 1, which = tid & 1;
        atomicAdd(&g_stats[(b * NG + g) * 2 + which], which ? gsq[g] : gsum[g]);
    }
}

// ---- Stage 5: GroupNorm apply + LeakyReLU: read fp16 g_yh, write fp32 out
__global__ void __launch_bounds__(256) norm_kernel(float* __restrict__ out,
                                                   const float* __restrict__ gamma,
                                                   const float* __restrict__ beta) {
    const int tid = threadIdx.x;
    const float invN = 1.0f / (8.0f * HWSZ);
    #pragma unroll
    for (int it = 0; it < 8; it++) {
        int ch = it * 2304 + blockIdx.x;           // chunk of 2048 elems, 18 per (b,co)
        int bco = ch / 18;                          // = b*64 + co
        int b = bco >> 6, co = bco & 63;
        int g = co >> 3;
        float mean = g_stats[(b * NG + g) * 2 + 0] * invN;
        float var = fmaxf(g_stats[(b * NG + g) * 2 + 1] * invN - mean * mean, 0.f);
        float sc = rsqrtf(var + EPSV) * gamma[co];
        float sh = beta[co] - mean * sc;
        size_t base = (size_t)ch * 2048 + tid * 8;
        v8h v = *(const v8h*)(g_yh + base);
        float vv[8];
        #pragma unroll
        for (int t = 0; t < 8; t++) {
            float a = (float)v[t] * sc + sh;
            vv[t] = a >= 0.f ? a : NSLOPE * a;
        }
        float4* op = (float4*)(out + base);
        op[0] = make_float4(vv[0], vv[1], vv[2], vv[3]);
        op[1] = make_float4(vv[4], vv[5], vv[6], vv[7]);
    }
}

extern "C" void kernel_launch(void* const* d_in, const int* in_sizes, int n_in,
                              void* d_out, int out_size, void* d_ws, size_t ws_size,
                              hipStream_t stream) {
    const float* x     = (const float*)d_in[0];
    const float* w1    = (const float*)d_in[1];
    const float* w2    = (const float*)d_in[2];
    const float* b2    = (const float*)d_in[3];
    const float* wts   = (const float*)d_in[4];
    const float* gamma = (const float*)d_in[5];
    const float* beta  = (const float*)d_in[6];
    float* out = (float*)d_out;

    dim3 tg(NTILE, BN);
    trans_pool_kernel<<<tg, 256, 0, stream>>>(x);
    attn_kernel<<<BN, 256, 0, stream>>>(w1, w2, b2);
    filt_kernel<<<144, 256, 0, stream>>>(wts);
    conv_kernel<<<NBLK, 256, 0, stream>>>();
    norm_kernel<<<2304, 256, 0, stream>>>(out, gamma, beta);
}